// Round 9
// baseline (56.264 us; speedup 1.0000x reference)
//
#include <hip/hip_runtime.h>
#include <math.h>

// Fuzzy capsule routing, MI355X — round 9: phase-1 coefficient reads moved to
// the SCALAR (SMEM) pipe. kh/cl wave-uniform -> readfirstlane'd global base ->
// s_load_dwordxN; DS pipe keeps only lp/r accesses. Sigma via rqv (R8 algebra).

#define NB 64
#define NK 20
#define NSPLIT 16
#define CPB 2
#define LPST 20           // lp row stride (floats)
#define RST 132           // r_s row stride
#define MROW 20           // mw row: [0..15]=-2Wg, [16]=|g|^2 (pad 20)
#define QROW 12           // MQ row: [0..9]=W.W^T pairs (pad 12)
#define WST 36            // wt_s row stride
#define PROW 18           // P row per k: [0..15]=u, [16]=s, [17]=rqv

__device__ __forceinline__ float frcp(float x){ return __builtin_amdgcn_rcpf(x); }
__device__ __forceinline__ float4 ldg4(const float* p){ return *(const float4*)p; }

// one mw row for (c,k): dp[0..15] = -2*W.g, dp[16] = |g|^2
__device__ __forceinline__ void build_row(const float* __restrict__ W,
                                          const float* g, float* __restrict__ dp)
{
    float w[16];
    {
        float4 a = ldg4(W+0), b = ldg4(W+4), cc = ldg4(W+8), d = ldg4(W+12);
        w[0]=a.x; w[1]=a.y; w[2]=a.z; w[3]=a.w;
        w[4]=b.x; w[5]=b.y; w[6]=b.z; w[7]=b.w;
        w[8]=cc.x; w[9]=cc.y; w[10]=cc.z; w[11]=cc.w;
        w[12]=d.x; w[13]=d.y; w[14]=d.z; w[15]=d.w;
    }
    float out[17];
    #pragma unroll
    for (int i=0;i<4;i++)
        #pragma unroll
        for (int j=0;j<4;j++){
            float a = w[j*4+0]*g[i*4+0] + w[j*4+1]*g[i*4+1]
                    + w[j*4+2]*g[i*4+2] + w[j*4+3]*g[i*4+3];
            out[i*4+j] = -2.f*a;
        }
    float cst = 0.f;
    #pragma unroll
    for (int x=0;x<16;x++) cst += g[x]*g[x];
    out[16] = cst;
    *(float4*)(dp+0)  = make_float4(out[0],out[1],out[2],out[3]);
    *(float4*)(dp+4)  = make_float4(out[4],out[5],out[6],out[7]);
    *(float4*)(dp+8)  = make_float4(out[8],out[9],out[10],out[11]);
    *(float4*)(dp+12) = make_float4(out[12],out[13],out[14],out[15]);
    *(float4*)(dp+16) = make_float4(out[16],0.f,0.f,0.f);
}

// ---------------- prep: mwA from g0 for all n; MQ once ----------------
__global__ __launch_bounds__(256)
void k_prep(const float* __restrict__ g_in, const float* __restrict__ wgt,
            float* __restrict__ mwA, float* __restrict__ MQ)
{
    const int q = blockIdx.x, n = blockIdx.y, tid = threadIdx.x;
    if (tid >= 160) return;
    const int c = tid/5, kloc = tid - c*5, k = q*5 + kloc;
    const float* W = wgt + k*512 + c*16;
    float g[16];
    {
        const float* gp = g_in + n*320 + k*16;
        float4 a = ldg4(gp+0), b = ldg4(gp+4), cc = ldg4(gp+8), d = ldg4(gp+12);
        g[0]=a.x; g[1]=a.y; g[2]=a.z; g[3]=a.w;
        g[4]=b.x; g[5]=b.y; g[6]=b.z; g[7]=b.w;
        g[8]=cc.x; g[9]=cc.y; g[10]=cc.z; g[11]=cc.w;
        g[12]=d.x; g[13]=d.y; g[14]=d.z; g[15]=d.w;
    }
    build_row(W, g, mwA + (size_t)(n*640 + c*NK + k)*MROW);
    if (n == 0){
        float w[16];
        {
            float4 a = ldg4(W+0), b = ldg4(W+4), cc = ldg4(W+8), d = ldg4(W+12);
            w[0]=a.x; w[1]=a.y; w[2]=a.z; w[3]=a.w;
            w[4]=b.x; w[5]=b.y; w[6]=b.z; w[7]=b.w;
            w[8]=cc.x; w[9]=cc.y; w[10]=cc.z; w[11]=cc.w;
            w[12]=d.x; w[13]=d.y; w[14]=d.z; w[15]=d.w;
        }
        float qv[10]; int p = 0;
        #pragma unroll
        for (int j=0;j<4;j++)
            #pragma unroll
            for (int jp=j;jp<4;jp++){
                float a = w[j*4+0]*w[jp*4+0] + w[j*4+1]*w[jp*4+1]
                        + w[j*4+2]*w[jp*4+2] + w[j*4+3]*w[jp*4+3];
                qv[p++] = (j==jp)? a : 2.f*a;
            }
        float* dp = MQ + (size_t)(c*NK + k)*QROW;
        *(float4*)(dp+0) = make_float4(qv[0],qv[1],qv[2],qv[3]);
        *(float4*)(dp+4) = make_float4(qv[4],qv[5],qv[6],qv[7]);
        *(float4*)(dp+8) = make_float4(qv[8],qv[9],0.f,0.f);
    }
}

// ---------------- reduce: P -> g -> next mw rows ----------------
__global__ __launch_bounds__(256)
void k_reduce(const float* __restrict__ P, const float* __restrict__ wgt,
              float* __restrict__ mwOut)
{
    const int q = blockIdx.x, n = blockIdx.y, tid = threadIdx.x;
    __shared__ float tmp_s[5*PROW];
    __shared__ float g_s[80];
    if (tid < 5*PROW){
        float acc = 0.f;
        const float* p = P + (size_t)n*NSPLIT*NK*PROW + q*5*PROW + tid;
        #pragma unroll
        for (int s=0;s<NSPLIT;s++) acc += p[s*NK*PROW];
        tmp_s[tid] = acc;
    }
    __syncthreads();
    if (tid < 80){
        int kloc = tid>>4, d = tid&15;
        g_s[tid] = tmp_s[kloc*PROW + d] / tmp_s[kloc*PROW + 16];
    }
    __syncthreads();
    if (tid < 160){
        const int c = tid/5, kloc = tid - c*5, k = q*5 + kloc;
        build_row(wgt + k*512 + c*16, &g_s[kloc*16],
                  mwOut + (size_t)(n*640 + c*NK + k)*MROW);
    }
}

// ---------------- final reduce: g3, sigma, a ----------------
__global__ __launch_bounds__(256)
void k_redfinal(const float* __restrict__ P, const float* __restrict__ beta,
                float* __restrict__ out)
{
    const int q = blockIdx.x, n = blockIdx.y, tid = threadIdx.x;
    __shared__ float tmp_s[5*PROW];
    if (tid < 5*PROW){
        float acc = 0.f;
        const float* p = P + (size_t)n*NSPLIT*NK*PROW + q*5*PROW + tid;
        #pragma unroll
        for (int s=0;s<NSPLIT;s++) acc += p[s*NK*PROW];
        tmp_s[tid] = acc;
    }
    __syncthreads();
    if (tid < 80){
        int kloc = tid>>4, d = tid&15;
        out[1280 + n*320 + q*80 + tid] = tmp_s[kloc*PROW + d] / tmp_s[kloc*PROW + 16];
    }
    if (tid < 5){
        const int k = q*5 + tid;
        float s   = tmp_s[tid*PROW + 16];
        float rqv = tmp_s[tid*PROW + 17];
        float usq = 0.f;
        #pragma unroll
        for (int d=0;d<16;d++){ float u = tmp_s[tid*PROW + d]; usq += u*u; }
        float is = 1.f/s;
        float sig = is*rqv - (is*is)*usq;     // (1/s)Sum r|V|^2 - |g3|^2
        float z = beta[k] - 0.5f*logf(sig);   // LAMBDA = 1
        out[n*NK + k] = 1.f/(1.f + expf(-z));
    }
}

// ---------------- routing iteration (MODE1: also accumulate rqv) ----------------
template<int MODE>
__global__ __launch_bounds__(256, MODE?3:4)
void k_route(const float* __restrict__ l, const float* __restrict__ wgt,
             const float* __restrict__ MQ, const float* __restrict__ mwIn,
             float* __restrict__ P)
{
    const int split = blockIdx.x, n = blockIdx.y, tid = threadIdx.x;
    const int c0 = split*CPB;

    __shared__ __align__(16) float lp_s[CPB*64*LPST];     // 2560
    __shared__ __align__(16) float r_s[NK*RST];           // 2640
    __shared__ __align__(16) float rqv_s[MODE? NK*RST:4]; // 2640 (MODE1)
    __shared__ __align__(16) float wt_s[NK*WST];          // 720
    __shared__ __align__(16) float red_s[4*NK*MROW];      // 1600
    __shared__ __align__(16) float rdp_s[256];

    // ---- stage: lp, W ----
    const float* lsrc = l + ((size_t)n*32 + c0)*1024;
    #pragma unroll
    for (int i=0;i<8;i++){
        int t = i*256 + tid;
        int cl = t>>10, dd = (t>>6)&15, wh = t&63;
        lp_s[(cl*64 + wh)*LPST + dd] = lsrc[t];
    }
    if (tid < 160){
        int k = tid>>3, part = tid&7, cl = part>>2, quad = part&3;
        *(float4*)&wt_s[k*WST + cl*16 + quad*4] =
            ldg4(wgt + k*512 + (c0+cl)*16 + quad*4);
    }
    __syncthreads();

    // ---- phase 1: wave-uniform (kh, cl); mw/MQ scalar loads from global ----
    {
        const int lane = tid & 63, wid = tid >> 6;
        const int kh = wid & 1, mh = wid >> 1;     // wave-uniform
        const int m  = mh*64 + lane;
        const float* lpr = &lp_s[m*LPST];
        float lp[16];
        #pragma unroll
        for (int q=0;q<4;q++){
            float4 v = *(const float4*)&lpr[q*4];
            lp[q*4+0]=v.x; lp[q*4+1]=v.y; lp[q*4+2]=v.z; lp[q*4+3]=v.w;
        }
        float QS[10];
        {
            int p=0;
            #pragma unroll
            for (int j=0;j<4;j++)
                #pragma unroll
                for (int jp=j;jp<4;jp++){
                    QS[p] = lp[j]*lp[jp] + lp[4+j]*lp[4+jp]
                          + lp[8+j]*lp[8+jp] + lp[12+j]*lp[12+jp];
                    p++;
                }
        }
        const int ub = __builtin_amdgcn_readfirstlane(((n*32 + c0 + mh)*NK + kh*10)*MROW);
        const int uq = __builtin_amdgcn_readfirstlane(((c0 + mh)*NK + kh*10)*QROW);
        const float* mwb = mwIn + ub;
        const float* mqb = MQ + uq;
        float invs[10], qvs[10];
        float rd = 0.f;
        #pragma unroll
        for (int i=0;i<10;i++){
            const float* row = mwb + i*MROW;
            const float* mq  = mqb + i*QROW;
            float qv = mq[0]*QS[0] + mq[1]*QS[1] + mq[2]*QS[2] + mq[3]*QS[3]
                     + mq[4]*QS[4] + mq[5]*QS[5] + mq[6]*QS[6] + mq[7]*QS[7]
                     + mq[8]*QS[8] + mq[9]*QS[9];
            float rn = row[16] + qv
                + row[0]*lp[0] + row[1]*lp[1] + row[2]*lp[2] + row[3]*lp[3]
                + row[4]*lp[4] + row[5]*lp[5] + row[6]*lp[6] + row[7]*lp[7]
                + row[8]*lp[8] + row[9]*lp[9] + row[10]*lp[10]+ row[11]*lp[11]
                + row[12]*lp[12]+ row[13]*lp[13]+ row[14]*lp[14]+ row[15]*lp[15];
            float inv = frcp(rn);
            invs[i] = inv;
            if (MODE) qvs[i] = qv;
            rd += inv;
        }
        rdp_s[kh*128 + m] = rd;
        __syncthreads();
        float ird = frcp(rdp_s[m] + rdp_s[128 + m]);
        #pragma unroll
        for (int i=0;i<10;i++){
            float t0 = invs[i]*ird;
            float r  = t0*t0;
            r_s[(kh*10+i)*RST + m] = r;
            if (MODE) rqv_s[(kh*10+i)*RST + m] = r*qvs[i];
        }
    }
    __syncthreads();

    // ---- phase 3: T[w,k,ij] = sum_m r*lp (+ rqv sum) ----
    const int k3 = tid & 31, mi = tid >> 5;
    const int kk = (k3 < NK)? k3 : k3 - NK;
    const int mbase = mi*16;
    float T[16]; float sacc = 0.f, rq = 0.f;
    #pragma unroll
    for (int d=0;d<16;d++) T[d]=0.f;

    auto acc_m = [&](float r, int m){
        const float* lr = &lp_s[m*LPST];
        float4 v0 = *(const float4*)&lr[0];
        float4 v1 = *(const float4*)&lr[4];
        float4 v2 = *(const float4*)&lr[8];
        float4 v3 = *(const float4*)&lr[12];
        T[0]+=r*v0.x; T[1]+=r*v0.y; T[2]+=r*v0.z; T[3]+=r*v0.w;
        T[4]+=r*v1.x; T[5]+=r*v1.y; T[6]+=r*v1.z; T[7]+=r*v1.w;
        T[8]+=r*v2.x; T[9]+=r*v2.y; T[10]+=r*v2.z; T[11]+=r*v2.w;
        T[12]+=r*v3.x; T[13]+=r*v3.y; T[14]+=r*v3.z; T[15]+=r*v3.w;
        sacc += r;
    };
    #pragma unroll
    for (int j4=0;j4<4;j4++){
        float4 rv = *(const float4*)&r_s[kk*RST + mbase + j4*4];
        acc_m(rv.x, mbase + j4*4 + 0);
        acc_m(rv.y, mbase + j4*4 + 1);
        acc_m(rv.z, mbase + j4*4 + 2);
        acc_m(rv.w, mbase + j4*4 + 3);
        if (MODE){
            float4 qv4 = *(const float4*)&rqv_s[kk*RST + mbase + j4*4];
            rq += qv4.x + qv4.y + qv4.z + qv4.w;
        }
    }
    #pragma unroll
    for (int d=0;d<16;d++) T[d] += __shfl_xor(T[d], 32, 64);
    sacc += __shfl_xor(sacc, 32, 64);
    if (MODE) rq += __shfl_xor(rq, 32, 64);
    if ((k3 < NK) && !(tid & 32)){
        float* row = &red_s[((tid>>6)*NK + k3)*MROW];
        *(float4*)(row+0)  = make_float4(T[0],T[1],T[2],T[3]);
        *(float4*)(row+4)  = make_float4(T[4],T[5],T[6],T[7]);
        *(float4*)(row+8)  = make_float4(T[8],T[9],T[10],T[11]);
        *(float4*)(row+12) = make_float4(T[12],T[13],T[14],T[15]);
        row[16] = sacc;
        row[17] = MODE? rq : 0.f;
    }
    __syncthreads();

    // ---- u-contract + P write (vectorized red_s reads) ----
    for (int t = tid; t < NK*PROW; t += 256){
        int k = t/PROW, x = t - k*PROW;
        float acc = 0.f;
        if (x >= 16){
            #pragma unroll
            for (int w=0;w<4;w++) acc += red_s[(w*NK+k)*MROW + x];
        } else {
            int i = x>>2, o = x&3;
            float wc0[4], wc1[4];
            #pragma unroll
            for (int j=0;j<4;j++){
                wc0[j] = wt_s[k*WST + j*4 + o];
                wc1[j] = wt_s[k*WST + 16 + j*4 + o];
            }
            #pragma unroll
            for (int w=0;w<4;w++){
                float4 rv = *(const float4*)&red_s[(w*NK+k)*MROW + i*4];
                const float* wcp = (w < 2)? wc0 : wc1;
                acc += rv.x*wcp[0] + rv.y*wcp[1] + rv.z*wcp[2] + rv.w*wcp[3];
            }
        }
        P[(size_t)(n*NSPLIT+split)*NK*PROW + t] = acc;
    }
}

extern "C" void kernel_launch(void* const* d_in, const int* in_sizes, int n_in,
                              void* d_out, int out_size, void* d_ws, size_t ws_size,
                              hipStream_t stream)
{
    const float* l    = (const float*)d_in[0];
    const float* g    = (const float*)d_in[1];
    const float* wgt  = (const float*)d_in[2];
    const float* beta = (const float*)d_in[3];
    float* out = (float*)d_out;
    float* ws  = (float*)d_ws;

    const size_t PSZ  = (size_t)NB * NSPLIT * NK * PROW;  // 368640
    const size_t MWSZ = (size_t)NB * 640 * MROW;          // 819200
    float* P    = ws;
    float* mwA  = P    + PSZ;
    float* mwB  = mwA  + MWSZ;
    float* MQ   = mwB  + MWSZ;                            // 7680

    dim3 gridR(NSPLIT, NB), gridS(4, NB), blk(256);
    k_prep<<<gridS, blk, 0, stream>>>(g, wgt, mwA, MQ);
    k_route<0><<<gridR, blk, 0, stream>>>(l, wgt, MQ, mwA, P);   // r1 (g0)
    k_reduce<<<gridS, blk, 0, stream>>>(P, wgt, mwB);            // g1 -> mwB
    k_route<0><<<gridR, blk, 0, stream>>>(l, wgt, MQ, mwB, P);   // r2 (g1)
    k_reduce<<<gridS, blk, 0, stream>>>(P, wgt, mwA);            // g2 -> mwA
    k_route<1><<<gridR, blk, 0, stream>>>(l, wgt, MQ, mwA, P);   // r3 (g2) + rqv
    k_redfinal<<<gridS, blk, 0, stream>>>(P, beta, out);         // g3, sigma, a
}

// Round 10
// 45.351 us; speedup vs baseline: 1.2406x; 1.2406x over previous
//
#include <hip/hip_runtime.h>
#include <math.h>

// Fuzzy capsule routing, MI355X — round 10: 4-launch chain.
// route1 builds coefficient rows from input g in-block; routes 2/3 reduce the
// previous pass's partials in-block (L2 reads) and build rows in LDS; only a
// tiny redfinal kernel remains. Phase 1 = R8 (LDS-staged, kh-split);
// phase 3 + vectorized u-contract = R9. Sigma via rqv algebra (R8).

#define NB 64
#define NK 20
#define NSPLIT 16
#define CPB 2
#define LPST 20           // lp row stride (floats)
#define RST 132           // r_s row stride
#define ROWF 28           // fused row: [0..15]=-2Wg, [16..25]=WW^T pairs, [26]=|g|^2, [27]=pad
#define WST 36            // wt_s row stride
#define PROW 18           // P row per k: [0..15]=u, [16]=s, [17]=rqv

__device__ __forceinline__ float frcp(float x){ return __builtin_amdgcn_rcpf(x); }
__device__ __forceinline__ float4 ldg4(const float* p){ return *(const float4*)p; }

// ---------------- final reduce: g3, sigma, a ----------------
__global__ __launch_bounds__(256)
void k_redfinal(const float* __restrict__ P, const float* __restrict__ beta,
                float* __restrict__ out)
{
    const int q = blockIdx.x, n = blockIdx.y, tid = threadIdx.x;
    __shared__ float tmp_s[5*PROW];
    if (tid < 5*PROW){
        float acc = 0.f;
        const float* p = P + (size_t)n*NSPLIT*NK*PROW + q*5*PROW + tid;
        #pragma unroll
        for (int s=0;s<NSPLIT;s++) acc += p[s*NK*PROW];
        tmp_s[tid] = acc;
    }
    __syncthreads();
    if (tid < 80){
        int kloc = tid>>4, d = tid&15;
        out[1280 + n*320 + q*80 + tid] = tmp_s[kloc*PROW + d] / tmp_s[kloc*PROW + 16];
    }
    if (tid < 5){
        const int k = q*5 + tid;
        float s   = tmp_s[tid*PROW + 16];
        float rqv = tmp_s[tid*PROW + 17];
        float usq = 0.f;
        #pragma unroll
        for (int d=0;d<16;d++){ float u = tmp_s[tid*PROW + d]; usq += u*u; }
        float is = 1.f/s;
        float sig = is*rqv - (is*is)*usq;     // (1/s)Sum r|V|^2 - |g3|^2
        float z = beta[k] - 0.5f*logf(sig);   // LAMBDA = 1
        out[n*NK + k] = 1.f/(1.f + expf(-z));
    }
}

// ---------------- routing iteration ----------------
// FIRST: g from g_in. Else: in-block reduce of Pprev -> g.
// MODE1: also accumulate rqv (for sigma).
template<int FIRST, int MODE>
__global__ __launch_bounds__(256, MODE?3:4)
void k_route(const float* __restrict__ l, const float* __restrict__ wgt,
             const float* __restrict__ g_in, const float* __restrict__ Pprev,
             float* __restrict__ Pout)
{
    const int split = blockIdx.x, n = blockIdx.y, tid = threadIdx.x;
    const int c0 = split*CPB;

    __shared__ __align__(16) float lp_s[CPB*64*LPST];     // 2560
    __shared__ __align__(16) float r_s[NK*RST];           // 2640
    __shared__ __align__(16) float rqv_s[MODE? NK*RST:4]; // 2640 (MODE1)
    __shared__ __align__(16) float mw_s[2*NK*ROWF];       // 1120
    __shared__ __align__(16) float wt_s[NK*WST];          // 720
    __shared__ __align__(16) float red_s[4*NK*PROW];      // 1440
    __shared__ __align__(16) float tmp_s[NK*PROW];        // 360
    __shared__ __align__(16) float g_s[NK*16];            // 320

    // ---- A: stage lp + W; issue g source loads ----
    const float* lsrc = l + ((size_t)n*32 + c0)*1024;
    #pragma unroll
    for (int i=0;i<8;i++){
        int t = i*256 + tid;
        int cl = t>>10, dd = (t>>6)&15, wh = t&63;
        lp_s[(cl*64 + wh)*LPST + dd] = lsrc[t];
    }
    if (tid < 160){
        int k = tid>>3, part = tid&7, cl = part>>2, quad = part&3;
        *(float4*)&wt_s[k*WST + cl*16 + quad*4] =
            ldg4(wgt + k*512 + (c0+cl)*16 + quad*4);
    }
    if (FIRST){
        for (int t = tid; t < NK*16; t += 256) g_s[t] = g_in[n*320 + t];
    } else {
        if (tid < 90){   // 90 float4 = 360 floats
            float4 acc = make_float4(0.f,0.f,0.f,0.f);
            const float* p = Pprev + (size_t)n*NSPLIT*NK*PROW + tid*4;
            #pragma unroll
            for (int s=0;s<NSPLIT;s++){
                float4 v = ldg4(p + s*NK*PROW);
                acc.x += v.x; acc.y += v.y; acc.z += v.z; acc.w += v.w;
            }
            *(float4*)&tmp_s[tid*4] = acc;
        }
    }
    __syncthreads();

    // ---- B: g from tmp (non-FIRST) ----
    if (!FIRST){
        for (int t = tid; t < NK*16; t += 256){
            int k = t>>4, d = t&15;
            g_s[t] = tmp_s[k*PROW + d] / tmp_s[k*PROW + 16];
        }
        __syncthreads();
    }

    // ---- C: build fused rows (threads 0..63 -> 40 rows) ----
    if (tid < 64){
        int cl = tid>>5, k = tid&31;
        if (k < NK){
            float w[16], g[16];
            #pragma unroll
            for (int q=0;q<4;q++){
                float4 wv = *(const float4*)&wt_s[k*WST + cl*16 + q*4];
                w[q*4+0]=wv.x; w[q*4+1]=wv.y; w[q*4+2]=wv.z; w[q*4+3]=wv.w;
                float4 gv = *(const float4*)&g_s[k*16 + q*4];
                g[q*4+0]=gv.x; g[q*4+1]=gv.y; g[q*4+2]=gv.z; g[q*4+3]=gv.w;
            }
            float* row = &mw_s[(cl*NK + k)*ROWF];
            #pragma unroll
            for (int i=0;i<4;i++)
                #pragma unroll
                for (int j=0;j<4;j++){
                    float a = w[j*4+0]*g[i*4+0] + w[j*4+1]*g[i*4+1]
                            + w[j*4+2]*g[i*4+2] + w[j*4+3]*g[i*4+3];
                    row[i*4+j] = -2.f*a;
                }
            int p = 0;
            #pragma unroll
            for (int j=0;j<4;j++)
                #pragma unroll
                for (int jp=j;jp<4;jp++){
                    float a = w[j*4+0]*w[jp*4+0] + w[j*4+1]*w[jp*4+1]
                            + w[j*4+2]*w[jp*4+2] + w[j*4+3]*w[jp*4+3];
                    row[16+p] = (j==jp)? a : 2.f*a;
                    p++;
                }
            float cst = 0.f;
            #pragma unroll
            for (int x=0;x<16;x++) cst += g[x]*g[x];
            row[26] = cst;
            row[27] = 0.f;
        }
    }
    __syncthreads();

    // ---- phase 1: thread=(m, khalf); 10 k each; rows from LDS ----
    {
        const int m = tid >> 1, kh = tid & 1;
        const float* lpr = &lp_s[m*LPST];
        float lp[16];
        #pragma unroll
        for (int q=0;q<4;q++){
            float4 v = *(const float4*)&lpr[q*4];
            lp[q*4+0]=v.x; lp[q*4+1]=v.y; lp[q*4+2]=v.z; lp[q*4+3]=v.w;
        }
        float QS[10];
        {
            int p=0;
            #pragma unroll
            for (int j=0;j<4;j++)
                #pragma unroll
                for (int jp=j;jp<4;jp++){
                    QS[p] = lp[j]*lp[jp] + lp[4+j]*lp[4+jp]
                          + lp[8+j]*lp[8+jp] + lp[12+j]*lp[12+jp];
                    p++;
                }
        }
        const int cl = tid >> 7;   // wave-uniform
        const float* mwb = &mw_s[(cl*NK + kh*10)*ROWF];
        float invs[10], qvs[10];
        float rd = 0.f;
        #pragma unroll
        for (int i=0;i<10;i++){
            const float* row = mwb + i*ROWF;
            float4 m0 = *(const float4*)(row+16);
            float4 m1 = *(const float4*)(row+20);
            float4 m2 = *(const float4*)(row+24);   // mq8, mq9, cst, pad
            float qv = m0.x*QS[0] + m0.y*QS[1] + m0.z*QS[2] + m0.w*QS[3]
                     + m1.x*QS[4] + m1.y*QS[5] + m1.z*QS[6] + m1.w*QS[7]
                     + m2.x*QS[8] + m2.y*QS[9];
            float4 w0 = *(const float4*)(row+0);
            float4 w1 = *(const float4*)(row+4);
            float4 w2 = *(const float4*)(row+8);
            float4 w3 = *(const float4*)(row+12);
            float rn = m2.z + qv
                + w0.x*lp[0] + w0.y*lp[1] + w0.z*lp[2] + w0.w*lp[3]
                + w1.x*lp[4] + w1.y*lp[5] + w1.z*lp[6] + w1.w*lp[7]
                + w2.x*lp[8] + w2.y*lp[9] + w2.z*lp[10]+ w2.w*lp[11]
                + w3.x*lp[12]+ w3.y*lp[13]+ w3.z*lp[14]+ w3.w*lp[15];
            float inv = frcp(rn);
            invs[i] = inv;
            if (MODE) qvs[i] = qv;
            rd += inv;
        }
        rd += __shfl_xor(rd, 1, 64);
        float ird = frcp(rd);
        #pragma unroll
        for (int i=0;i<10;i++){
            float t0 = invs[i]*ird;
            float r  = t0*t0;
            r_s[(kh*10+i)*RST + m] = r;
            if (MODE) rqv_s[(kh*10+i)*RST + m] = r*qvs[i];
        }
    }
    __syncthreads();

    // ---- phase 3: T[w,k,ij] = sum_m r*lp (+ rqv sum) ----
    const int k3 = tid & 31, mi = tid >> 5;
    const int kk = (k3 < NK)? k3 : k3 - NK;
    const int mbase = mi*16;
    float T[16]; float sacc = 0.f, rq = 0.f;
    #pragma unroll
    for (int d=0;d<16;d++) T[d]=0.f;

    auto acc_m = [&](float r, int m){
        const float* lr = &lp_s[m*LPST];
        float4 v0 = *(const float4*)&lr[0];
        float4 v1 = *(const float4*)&lr[4];
        float4 v2 = *(const float4*)&lr[8];
        float4 v3 = *(const float4*)&lr[12];
        T[0]+=r*v0.x; T[1]+=r*v0.y; T[2]+=r*v0.z; T[3]+=r*v0.w;
        T[4]+=r*v1.x; T[5]+=r*v1.y; T[6]+=r*v1.z; T[7]+=r*v1.w;
        T[8]+=r*v2.x; T[9]+=r*v2.y; T[10]+=r*v2.z; T[11]+=r*v2.w;
        T[12]+=r*v3.x; T[13]+=r*v3.y; T[14]+=r*v3.z; T[15]+=r*v3.w;
        sacc += r;
    };
    #pragma unroll
    for (int j4=0;j4<4;j4++){
        float4 rv = *(const float4*)&r_s[kk*RST + mbase + j4*4];
        acc_m(rv.x, mbase + j4*4 + 0);
        acc_m(rv.y, mbase + j4*4 + 1);
        acc_m(rv.z, mbase + j4*4 + 2);
        acc_m(rv.w, mbase + j4*4 + 3);
        if (MODE){
            float4 qv4 = *(const float4*)&rqv_s[kk*RST + mbase + j4*4];
            rq += qv4.x + qv4.y + qv4.z + qv4.w;
        }
    }
    #pragma unroll
    for (int d=0;d<16;d++) T[d] += __shfl_xor(T[d], 32, 64);
    sacc += __shfl_xor(sacc, 32, 64);
    if (MODE) rq += __shfl_xor(rq, 32, 64);
    if ((k3 < NK) && !(tid & 32)){
        float* row = &red_s[((tid>>6)*NK + k3)*PROW];
        *(float4*)(row+0)  = make_float4(T[0],T[1],T[2],T[3]);
        *(float4*)(row+4)  = make_float4(T[4],T[5],T[6],T[7]);
        *(float4*)(row+8)  = make_float4(T[8],T[9],T[10],T[11]);
        *(float4*)(row+12) = make_float4(T[12],T[13],T[14],T[15]);
        row[16] = sacc;
        row[17] = MODE? rq : 0.f;
    }
    __syncthreads();

    // ---- u-contract + P write (vectorized red_s reads) ----
    for (int t = tid; t < NK*PROW; t += 256){
        int k = t/PROW, x = t - k*PROW;
        float acc = 0.f;
        if (x >= 16){
            #pragma unroll
            for (int w=0;w<4;w++) acc += red_s[(w*NK+k)*PROW + x];
        } else {
            int i = x>>2, o = x&3;
            float wc0[4], wc1[4];
            #pragma unroll
            for (int j=0;j<4;j++){
                wc0[j] = wt_s[k*WST + j*4 + o];
                wc1[j] = wt_s[k*WST + 16 + j*4 + o];
            }
            #pragma unroll
            for (int w=0;w<4;w++){
                float4 rv = *(const float4*)&red_s[(w*NK+k)*PROW + i*4];
                const float* wcp = (w < 2)? wc0 : wc1;
                acc += rv.x*wcp[0] + rv.y*wcp[1] + rv.z*wcp[2] + rv.w*wcp[3];
            }
        }
        Pout[(size_t)(n*NSPLIT+split)*NK*PROW + t] = acc;
    }
}

extern "C" void kernel_launch(void* const* d_in, const int* in_sizes, int n_in,
                              void* d_out, int out_size, void* d_ws, size_t ws_size,
                              hipStream_t stream)
{
    const float* l    = (const float*)d_in[0];
    const float* g    = (const float*)d_in[1];
    const float* wgt  = (const float*)d_in[2];
    const float* beta = (const float*)d_in[3];
    float* out = (float*)d_out;
    float* ws  = (float*)d_ws;

    const size_t PSZ = (size_t)NB * NSPLIT * NK * PROW;   // 368640
    float* PA = ws;
    float* PB = PA + PSZ;

    dim3 gridR(NSPLIT, NB), gridS(4, NB), blk(256);
    k_route<1,0><<<gridR, blk, 0, stream>>>(l, wgt, g, nullptr, PA);  // r1 (g0)
    k_route<0,0><<<gridR, blk, 0, stream>>>(l, wgt, nullptr, PA, PB); // r2 (g1)
    k_route<0,1><<<gridR, blk, 0, stream>>>(l, wgt, nullptr, PB, PA); // r3 (g2) + rqv
    k_redfinal<<<gridS, blk, 0, stream>>>(PA, beta, out);             // g3, sigma, a
}

// Round 11
// 42.030 us; speedup vs baseline: 1.3387x; 1.0790x over previous
//
#include <hip/hip_runtime.h>
#include <math.h>

// Fuzzy capsule routing, MI355X — round 11: 2-m-per-thread row amortization.
// CPB=4 (256 m/block, NSPLIT=8): phase-1 thread owns (m-pair, kh) and reuses
// each coefficient row (28f, registers) for BOTH m -> row b128 issues per
// (k,m) pair halved. rqv wave-reduced via shfl (no rqv_s mirror). lp in
// paired-row stride-36 layout. Wave w == cl. 4 launches as R10.

#define NB 64
#define NK 20
#define NSPLIT 8
#define CPB 4
#define LPP 36            // lp pair-row stride: [mp][ m&1 ? 16..31 : 0..15 ]
#define RST 260           // r_s row stride (256 m + pad, 16B aligned)
#define ROWF 28           // fused row: [0..15]=-2Wg, [16..25]=WW^T, [26]=|g|^2
#define PROW 18           // P row per k: [0..15]=u, [16]=s, [17]=rqv

__device__ __forceinline__ float frcp(float x){ return __builtin_amdgcn_rcpf(x); }
__device__ __forceinline__ float4 ldg4(const float* p){ return *(const float4*)p; }

// ---------------- final reduce: g3, sigma, a ----------------
__global__ __launch_bounds__(256)
void k_redfinal(const float* __restrict__ P, const float* __restrict__ beta,
                float* __restrict__ out)
{
    const int q = blockIdx.x, n = blockIdx.y, tid = threadIdx.x;
    __shared__ float tmp_s[5*PROW];
    if (tid < 5*PROW){
        float acc = 0.f;
        const float* p = P + (size_t)n*NSPLIT*NK*PROW + q*5*PROW + tid;
        #pragma unroll
        for (int s=0;s<NSPLIT;s++) acc += p[s*NK*PROW];
        tmp_s[tid] = acc;
    }
    __syncthreads();
    if (tid < 80){
        int kloc = tid>>4, d = tid&15;
        out[1280 + n*320 + q*80 + tid] = tmp_s[kloc*PROW + d] / tmp_s[kloc*PROW + 16];
    }
    if (tid < 5){
        const int k = q*5 + tid;
        float s   = tmp_s[tid*PROW + 16];
        float rqv = tmp_s[tid*PROW + 17];
        float usq = 0.f;
        #pragma unroll
        for (int d=0;d<16;d++){ float u = tmp_s[tid*PROW + d]; usq += u*u; }
        float is = 1.f/s;
        float sig = is*rqv - (is*is)*usq;     // (1/s)Sum r|V|^2 - |g3|^2
        float z = beta[k] - 0.5f*logf(sig);   // LAMBDA = 1
        out[n*NK + k] = 1.f/(1.f + expf(-z));
    }
}

// ---------------- routing iteration ----------------
// FIRST: g from g_in. Else: in-block reduce of Pprev (red_s as tmp) -> g.
// MODE1: also accumulate rqv (wave-reduced in phase 1).
template<int FIRST, int MODE>
__global__ __launch_bounds__(256, 2)
void k_route(const float* __restrict__ l, const float* __restrict__ wgt,
             const float* __restrict__ g_in, const float* __restrict__ Pprev,
             float* __restrict__ Pout)
{
    const int split = blockIdx.x, n = blockIdx.y, tid = threadIdx.x;
    const int c0 = split*CPB;

    __shared__ __align__(16) float lp_s[128*LPP];        // 4608
    __shared__ __align__(16) float r_s[NK*RST];          // 5200
    __shared__ __align__(16) float mw_s[CPB*NK*ROWF];    // 2240
    __shared__ __align__(16) float wt_s[CPB*NK*16];      // 1280
    __shared__ __align__(16) float red_s[4*NK*PROW];     // 1440 (tmp alias early)
    __shared__ __align__(16) float rqw_s[4*24];          // 96
    __shared__ __align__(16) float g_s[NK*16];           // 320

    // ---- A: stage lp (paired rows), W; g source ----
    const float* lsrc = l + ((size_t)n*32 + c0)*1024;
    #pragma unroll
    for (int i=0;i<16;i++){
        int t = i*256 + tid;
        int cl = t>>10, dd = (t>>6)&15, wh = t&63;
        int m = cl*64 + wh;
        lp_s[(m>>1)*LPP + (m&1)*16 + dd] = lsrc[t];
    }
    #pragma unroll
    for (int f0=0; f0<2; f0++){
        int f = f0*256 + tid;                 // float4 index 0..319
        if (f < 320){
            int row = f>>2, q = f&3;
            int cl = row/20, k = row - cl*20;
            *(float4*)&wt_s[row*16 + q*4] = ldg4(wgt + k*512 + (c0+cl)*16 + q*4);
        }
    }
    if (FIRST){
        for (int t = tid; t < NK*16; t += 256) g_s[t] = g_in[n*320 + t];
    } else {
        if (tid < 90){   // 90 float4 = 360 floats -> red_s (tmp)
            float4 acc = make_float4(0.f,0.f,0.f,0.f);
            const float* p = Pprev + (size_t)n*NSPLIT*NK*PROW + tid*4;
            #pragma unroll
            for (int s=0;s<NSPLIT;s++){
                float4 v = ldg4(p + s*NK*PROW);
                acc.x += v.x; acc.y += v.y; acc.z += v.z; acc.w += v.w;
            }
            *(float4*)&red_s[tid*4] = acc;
        }
    }
    __syncthreads();

    // ---- B: g from tmp (non-FIRST) ----
    if (!FIRST){
        for (int t = tid; t < NK*16; t += 256){
            int k = t>>4, d = t&15;
            g_s[t] = red_s[k*PROW + d] / red_s[k*PROW + 16];
        }
        __syncthreads();
    }

    // ---- C: build fused rows (80 rows) ----
    if (tid < CPB*NK){
        int cl = tid/20, k = tid - cl*20;
        float w[16], g[16];
        #pragma unroll
        for (int q=0;q<4;q++){
            float4 wv = *(const float4*)&wt_s[(cl*20+k)*16 + q*4];
            w[q*4+0]=wv.x; w[q*4+1]=wv.y; w[q*4+2]=wv.z; w[q*4+3]=wv.w;
            float4 gv = *(const float4*)&g_s[k*16 + q*4];
            g[q*4+0]=gv.x; g[q*4+1]=gv.y; g[q*4+2]=gv.z; g[q*4+3]=gv.w;
        }
        float* row = &mw_s[(cl*20 + k)*ROWF];
        #pragma unroll
        for (int i=0;i<4;i++)
            #pragma unroll
            for (int j=0;j<4;j++){
                float a = w[j*4+0]*g[i*4+0] + w[j*4+1]*g[i*4+1]
                        + w[j*4+2]*g[i*4+2] + w[j*4+3]*g[i*4+3];
                row[i*4+j] = -2.f*a;
            }
        int p = 0;
        #pragma unroll
        for (int j=0;j<4;j++)
            #pragma unroll
            for (int jp=j;jp<4;jp++){
                float a = w[j*4+0]*w[jp*4+0] + w[j*4+1]*w[jp*4+1]
                        + w[j*4+2]*w[jp*4+2] + w[j*4+3]*w[jp*4+3];
                row[16+p] = (j==jp)? a : 2.f*a;
                p++;
            }
        float cst = 0.f;
        #pragma unroll
        for (int x=0;x<16;x++) cst += g[x]*g[x];
        row[26] = cst;
        row[27] = 0.f;
    }
    __syncthreads();

    // ---- phase 1: thread=(m-pair, kh); rows reused for both m ----
    {
        const int mp = tid >> 1, kh = tid & 1;
        const float* lpr = &lp_s[mp*LPP];
        float lp0[16], lp1[16];
        #pragma unroll
        for (int q=0;q<4;q++){
            float4 v0 = *(const float4*)&lpr[q*4];
            lp0[q*4+0]=v0.x; lp0[q*4+1]=v0.y; lp0[q*4+2]=v0.z; lp0[q*4+3]=v0.w;
            float4 v1 = *(const float4*)&lpr[16 + q*4];
            lp1[q*4+0]=v1.x; lp1[q*4+1]=v1.y; lp1[q*4+2]=v1.z; lp1[q*4+3]=v1.w;
        }
        float QS0[10], QS1[10];
        {
            int p=0;
            #pragma unroll
            for (int j=0;j<4;j++)
                #pragma unroll
                for (int jp=j;jp<4;jp++){
                    QS0[p] = lp0[j]*lp0[jp] + lp0[4+j]*lp0[4+jp]
                           + lp0[8+j]*lp0[8+jp] + lp0[12+j]*lp0[12+jp];
                    QS1[p] = lp1[j]*lp1[jp] + lp1[4+j]*lp1[4+jp]
                           + lp1[8+j]*lp1[8+jp] + lp1[12+j]*lp1[12+jp];
                    p++;
                }
        }
        const int cl = tid >> 6;   // wave id == cl (wave covers 32 mp = 64 m)
        const float* mwb = &mw_s[(cl*20 + kh*10)*ROWF];
        float invs0[10], invs1[10], qvs0[10], qvs1[10];
        float rd0 = 0.f, rd1 = 0.f;
        #pragma unroll
        for (int i=0;i<10;i++){
            const float* row = mwb + i*ROWF;
            float4 w0 = *(const float4*)(row+0);
            float4 w1 = *(const float4*)(row+4);
            float4 w2 = *(const float4*)(row+8);
            float4 w3 = *(const float4*)(row+12);
            float4 a0 = *(const float4*)(row+16);
            float4 a1 = *(const float4*)(row+20);
            float4 a2 = *(const float4*)(row+24);   // mq8, mq9, cst, pad
            float qv0 = a0.x*QS0[0] + a0.y*QS0[1] + a0.z*QS0[2] + a0.w*QS0[3]
                      + a1.x*QS0[4] + a1.y*QS0[5] + a1.z*QS0[6] + a1.w*QS0[7]
                      + a2.x*QS0[8] + a2.y*QS0[9];
            float qv1 = a0.x*QS1[0] + a0.y*QS1[1] + a0.z*QS1[2] + a0.w*QS1[3]
                      + a1.x*QS1[4] + a1.y*QS1[5] + a1.z*QS1[6] + a1.w*QS1[7]
                      + a2.x*QS1[8] + a2.y*QS1[9];
            float rn0 = a2.z + qv0
                + w0.x*lp0[0] + w0.y*lp0[1] + w0.z*lp0[2] + w0.w*lp0[3]
                + w1.x*lp0[4] + w1.y*lp0[5] + w1.z*lp0[6] + w1.w*lp0[7]
                + w2.x*lp0[8] + w2.y*lp0[9] + w2.z*lp0[10]+ w2.w*lp0[11]
                + w3.x*lp0[12]+ w3.y*lp0[13]+ w3.z*lp0[14]+ w3.w*lp0[15];
            float rn1 = a2.z + qv1
                + w0.x*lp1[0] + w0.y*lp1[1] + w0.z*lp1[2] + w0.w*lp1[3]
                + w1.x*lp1[4] + w1.y*lp1[5] + w1.z*lp1[6] + w1.w*lp1[7]
                + w2.x*lp1[8] + w2.y*lp1[9] + w2.z*lp1[10]+ w2.w*lp1[11]
                + w3.x*lp1[12]+ w3.y*lp1[13]+ w3.z*lp1[14]+ w3.w*lp1[15];
            float i0 = frcp(rn0), i1 = frcp(rn1);
            invs0[i] = i0; invs1[i] = i1;
            if (MODE){ qvs0[i] = qv0; qvs1[i] = qv1; }
            rd0 += i0; rd1 += i1;
        }
        rd0 += __shfl_xor(rd0, 1, 64);
        rd1 += __shfl_xor(rd1, 1, 64);
        float ird0 = frcp(rd0), ird1 = frcp(rd1);
        #pragma unroll
        for (int i=0;i<10;i++){
            float t0 = invs0[i]*ird0, t1 = invs1[i]*ird1;
            float r0 = t0*t0, r1 = t1*t1;
            *(float2*)&r_s[(kh*10+i)*RST + mp*2] = make_float2(r0, r1);
            if (MODE){
                float rqp = r0*qvs0[i] + r1*qvs1[i];
                rqp += __shfl_xor(rqp, 2, 64);
                rqp += __shfl_xor(rqp, 4, 64);
                rqp += __shfl_xor(rqp, 8, 64);
                rqp += __shfl_xor(rqp, 16, 64);
                rqp += __shfl_xor(rqp, 32, 64);
                if ((tid & 62) == 0)              // lanes 0,1 of the wave
                    rqw_s[cl*24 + kh*10 + i] = rqp;
            }
        }
    }
    __syncthreads();

    // ---- phase 3: T[w,k,ij] = sum over this wave's 64 m of r*lp ----
    const int k3 = tid & 31, mi = tid >> 5;      // mi 0..7, 32 m each
    const int kk = (k3 < NK)? k3 : k3 - NK;
    const int mbase = mi*32;
    float T[16]; float sacc = 0.f;
    #pragma unroll
    for (int d=0;d<16;d++) T[d]=0.f;

    auto acc_m = [&](float r, int m){
        const float* lr = &lp_s[(m>>1)*LPP + (m&1)*16];
        float4 v0 = *(const float4*)&lr[0];
        float4 v1 = *(const float4*)&lr[4];
        float4 v2 = *(const float4*)&lr[8];
        float4 v3 = *(const float4*)&lr[12];
        T[0]+=r*v0.x; T[1]+=r*v0.y; T[2]+=r*v0.z; T[3]+=r*v0.w;
        T[4]+=r*v1.x; T[5]+=r*v1.y; T[6]+=r*v1.z; T[7]+=r*v1.w;
        T[8]+=r*v2.x; T[9]+=r*v2.y; T[10]+=r*v2.z; T[11]+=r*v2.w;
        T[12]+=r*v3.x; T[13]+=r*v3.y; T[14]+=r*v3.z; T[15]+=r*v3.w;
        sacc += r;
    };
    #pragma unroll
    for (int j4=0;j4<8;j4++){
        float4 rv = *(const float4*)&r_s[kk*RST + mbase + j4*4];
        acc_m(rv.x, mbase + j4*4 + 0);
        acc_m(rv.y, mbase + j4*4 + 1);
        acc_m(rv.z, mbase + j4*4 + 2);
        acc_m(rv.w, mbase + j4*4 + 3);
    }
    #pragma unroll
    for (int d=0;d<16;d++) T[d] += __shfl_xor(T[d], 32, 64);
    sacc += __shfl_xor(sacc, 32, 64);
    if ((k3 < NK) && !(tid & 32)){
        float* row = &red_s[((tid>>6)*NK + k3)*PROW];
        *(float4*)(row+0)  = make_float4(T[0],T[1],T[2],T[3]);
        *(float4*)(row+4)  = make_float4(T[4],T[5],T[6],T[7]);
        *(float4*)(row+8)  = make_float4(T[8],T[9],T[10],T[11]);
        *(float4*)(row+12) = make_float4(T[12],T[13],T[14],T[15]);
        row[16] = sacc;
    }
    __syncthreads();

    // ---- u-contract + P write (wave w == cl) ----
    for (int t = tid; t < NK*PROW; t += 256){
        int k = t/PROW, x = t - k*PROW;
        float acc = 0.f;
        if (x == 17){
            if (MODE)
                acc = rqw_s[0*24+k] + rqw_s[1*24+k] + rqw_s[2*24+k] + rqw_s[3*24+k];
        } else if (x == 16){
            #pragma unroll
            for (int w=0;w<4;w++) acc += red_s[(w*NK+k)*PROW + 16];
        } else {
            int i = x>>2, o = x&3;
            #pragma unroll
            for (int w=0;w<4;w++){
                float4 rv = *(const float4*)&red_s[(w*NK+k)*PROW + i*4];
                acc += rv.x*wt_s[(w*20+k)*16 + 0*4 + o]
                     + rv.y*wt_s[(w*20+k)*16 + 1*4 + o]
                     + rv.z*wt_s[(w*20+k)*16 + 2*4 + o]
                     + rv.w*wt_s[(w*20+k)*16 + 3*4 + o];
            }
        }
        Pout[(size_t)(n*NSPLIT+split)*NK*PROW + t] = acc;
    }
}

extern "C" void kernel_launch(void* const* d_in, const int* in_sizes, int n_in,
                              void* d_out, int out_size, void* d_ws, size_t ws_size,
                              hipStream_t stream)
{
    const float* l    = (const float*)d_in[0];
    const float* g    = (const float*)d_in[1];
    const float* wgt  = (const float*)d_in[2];
    const float* beta = (const float*)d_in[3];
    float* out = (float*)d_out;
    float* ws  = (float*)d_ws;

    const size_t PSZ = (size_t)NB * NSPLIT * NK * PROW;   // 184320
    float* PA = ws;
    float* PB = PA + PSZ;

    dim3 gridR(NSPLIT, NB), gridS(4, NB), blk(256);
    k_route<1,0><<<gridR, blk, 0, stream>>>(l, wgt, g, nullptr, PA);  // r1 (g0)
    k_route<0,0><<<gridR, blk, 0, stream>>>(l, wgt, nullptr, PA, PB); // r2 (g1)
    k_route<0,1><<<gridR, blk, 0, stream>>>(l, wgt, nullptr, PB, PA); // r3 (g2) + rqv
    k_redfinal<<<gridS, blk, 0, stream>>>(PA, beta, out);             // g3, sigma, a
}